// Round 1
// baseline (385.303 us; speedup 1.0000x reference)
//
#include <hip/hip_runtime.h>
#include <math.h>

#define N_NODES 50000
#define N_EDGES 800000
#define E_TOT   (N_EDGES + N_NODES)
#define IN_DIM  128
#define HID     128      // HEADS*HIDDEN (layer-1 output width)
#define ODIM    64
#define NEG     0.2f
#define NB1     ((N_NODES + 255) / 256)   // scan blocks = 196

__device__ __forceinline__ float lrelu(float x) { return x >= 0.f ? x : NEG * x; }

// ---------- edge-index dtype detection (int32 vs int64) ----------
__global__ void k_detect(const void* ei, int* flag) {
  if (threadIdx.x == 0 && blockIdx.x == 0) {
    const int* p = (const int*)ei;
    int allz = 1;
    for (int i = 0; i < 64; ++i) if (p[2 * i + 1] != 0) { allz = 0; break; }
    *flag = allz;  // 1 => buffer is int64
  }
}

__device__ __forceinline__ int e_src(const void* ei, int f, int e) {
  if (e >= N_EDGES) return e - N_EDGES;              // self loop
  return f ? (int)((const long long*)ei)[e] : ((const int*)ei)[e];
}
__device__ __forceinline__ int e_dst(const void* ei, int f, int e) {
  if (e >= N_EDGES) return e - N_EDGES;              // self loop
  return f ? (int)((const long long*)ei)[N_EDGES + e] : ((const int*)ei)[N_EDGES + e];
}

// ---------- CSR build ----------
__global__ void k_hist(const void* ei, const int* flag, int* deg) {
  int e = blockIdx.x * 256 + threadIdx.x;
  if (e >= E_TOT) return;
  atomicAdd(&deg[e_dst(ei, *flag, e)], 1);
}

__global__ void k_scan1(const int* __restrict__ deg, int* __restrict__ offs, int* __restrict__ bsums) {
  __shared__ int sm[256];
  int t = threadIdx.x, i = blockIdx.x * 256 + t;
  int v = (i < N_NODES) ? deg[i] : 0;
  sm[t] = v;
  __syncthreads();
  for (int o = 1; o < 256; o <<= 1) {
    int add = (t >= o) ? sm[t - o] : 0;
    __syncthreads();
    sm[t] += add;
    __syncthreads();
  }
  if (i < N_NODES) offs[i] = sm[t] - v;   // exclusive
  if (t == 255) bsums[blockIdx.x] = sm[255];
}

__global__ void k_scan2(int* bsums) {
  __shared__ int sm[256];
  int t = threadIdx.x;
  int v = (t < NB1) ? bsums[t] : 0;
  sm[t] = v;
  __syncthreads();
  for (int o = 1; o < 256; o <<= 1) {
    int add = (t >= o) ? sm[t - o] : 0;
    __syncthreads();
    sm[t] += add;
    __syncthreads();
  }
  if (t < NB1) bsums[t] = sm[t] - v;      // exclusive
}

__global__ void k_scan3(int* __restrict__ offs, const int* __restrict__ bsums) {
  int i = blockIdx.x * 256 + threadIdx.x;
  if (i < N_NODES) offs[i] += bsums[blockIdx.x];
  if (i == 0) offs[N_NODES] = E_TOT;
}

__global__ void k_scatter(const void* ei, const int* __restrict__ flag, const int* __restrict__ offs,
                          int* __restrict__ cur, int* __restrict__ srcs) {
  int e = blockIdx.x * 256 + threadIdx.x;
  if (e >= E_TOT) return;
  int f = *flag;
  int d = e_dst(ei, f, e);
  int pos = offs[d] + atomicAdd(&cur[d], 1);
  srcs[pos] = e_src(ei, f, e);
}

// ---------- GEMM1: h1[N,128] = x[N,128] @ W1[128,128] ----------
// 256 thr: col = t&127, ng = t>>7; 8 nodes/chunk (4 per thread), W half-staged (32KB) + xs (4KB)
__global__ __launch_bounds__(256) void k_gemm1(const float* __restrict__ x, const float* __restrict__ W,
                                               float* __restrict__ h1) {
  __shared__ float Wl[64 * HID];     // 32 KB (rows kb..kb+63)
  __shared__ float xs[8 * IN_DIM];   // 4 KB
  int t = threadIdx.x, col = t & 127, ng = t >> 7;
  for (int chunk = blockIdx.x; chunk < N_NODES / 8; chunk += gridDim.x) {
    int base = chunk * 8;
    __syncthreads();
    for (int i = t; i < 8 * IN_DIM; i += 256) xs[i] = x[base * IN_DIM + i];
    float a0 = 0, a1 = 0, a2 = 0, a3 = 0;
    for (int kb = 0; kb < IN_DIM; kb += 64) {
      __syncthreads();
      for (int i = t; i < 64 * HID; i += 256) Wl[i] = W[kb * HID + i];
      __syncthreads();
      #pragma unroll 8
      for (int kk = 0; kk < 64; ++kk) {
        int k = kb + kk;
        float w = Wl[kk * HID + col];
        a0 = fmaf(xs[(ng + 0) * IN_DIM + k], w, a0);
        a1 = fmaf(xs[(ng + 2) * IN_DIM + k], w, a1);
        a2 = fmaf(xs[(ng + 4) * IN_DIM + k], w, a2);
        a3 = fmaf(xs[(ng + 6) * IN_DIM + k], w, a3);
      }
    }
    h1[(base + ng + 0) * HID + col] = a0;
    h1[(base + ng + 2) * HID + col] = a1;
    h1[(base + ng + 4) * HID + col] = a2;
    h1[(base + ng + 6) * HID + col] = a3;
  }
}

// ---------- GEMM2: h2[N,64] = out1[N,128] @ W2[128,64] ----------
__global__ __launch_bounds__(256) void k_gemm2(const float* __restrict__ x, const float* __restrict__ W,
                                               float* __restrict__ h2) {
  __shared__ float Wl[HID * ODIM];   // 32 KB, staged once
  __shared__ float xs[16 * HID];     // 8 KB
  int t = threadIdx.x, col = t & 63, ng = t >> 6;   // ng 0..3
  for (int i = t; i < HID * ODIM; i += 256) Wl[i] = W[i];
  for (int chunk = blockIdx.x; chunk < N_NODES / 16; chunk += gridDim.x) {
    int base = chunk * 16;
    __syncthreads();
    for (int i = t; i < 16 * HID; i += 256) xs[i] = x[base * HID + i];
    __syncthreads();
    float a0 = 0, a1 = 0, a2 = 0, a3 = 0;
    #pragma unroll 8
    for (int k = 0; k < HID; ++k) {
      float w = Wl[k * ODIM + col];
      a0 = fmaf(xs[(ng +  0) * HID + k], w, a0);
      a1 = fmaf(xs[(ng +  4) * HID + k], w, a1);
      a2 = fmaf(xs[(ng +  8) * HID + k], w, a2);
      a3 = fmaf(xs[(ng + 12) * HID + k], w, a3);
    }
    h2[(base + ng +  0) * ODIM + col] = a0;
    h2[(base + ng +  4) * ODIM + col] = a1;
    h2[(base + ng +  8) * ODIM + col] = a2;
    h2[(base + ng + 12) * ODIM + col] = a3;
  }
}

// ---------- attention logits: als/ald ----------
__global__ __launch_bounds__(256) void k_al1(const float* __restrict__ h1, const float* __restrict__ asrc,
                                             const float* __restrict__ adst, float* __restrict__ als,
                                             float* __restrict__ ald) {
  int t = threadIdx.x;
  int n = blockIdx.x * 2 + (t >> 7);
  int col = t & 127;
  float v = h1[n * HID + col];
  float s = v * asrc[col], d = v * adst[col];   // a_src1 flat [4*32]
  #pragma unroll
  for (int o = 16; o >= 1; o >>= 1) { s += __shfl_xor(s, o); d += __shfl_xor(d, o); }
  if ((col & 31) == 0) { als[n * 4 + (col >> 5)] = s; ald[n * 4 + (col >> 5)] = d; }
}

__global__ __launch_bounds__(256) void k_al2(const float* __restrict__ h2, const float* __restrict__ asrc,
                                             const float* __restrict__ adst, float* __restrict__ als,
                                             float* __restrict__ ald) {
  int t = threadIdx.x;
  int n = blockIdx.x * 4 + (t >> 6);
  int col = t & 63;
  float v = h2[n * ODIM + col];
  float s = v * asrc[col], d = v * adst[col];
  #pragma unroll
  for (int o = 32; o >= 1; o >>= 1) { s += __shfl_xor(s, o); d += __shfl_xor(d, o); }
  if (col == 0) { als[n] = s; ald[n] = d; }
}

// ---------- layer-1 softmax + aggregate: one block (128 thr) per dst node ----------
__global__ __launch_bounds__(128) void k_agg1(const float* __restrict__ h1, const float* __restrict__ als,
                                              const float* __restrict__ ald, const int* __restrict__ offs,
                                              const int* __restrict__ srcs, const float* __restrict__ b1,
                                              float* __restrict__ out1) {
  __shared__ int sl[256];
  __shared__ float se[4 * 256];
  int n = blockIdx.x, t = threadIdx.x;
  int head = t >> 5;
  int off0 = offs[n], deg = offs[n + 1] - off0;
  float aldv = ald[n * 4 + head];
  float m = -INFINITY, den = 0.f, num = 0.f;
  if (deg <= 256) {
    for (int j = t; j < deg; j += 128) sl[j] = srcs[off0 + j];
    __syncthreads();
    for (int j = 0; j < deg; ++j) {
      float e = lrelu(als[sl[j] * 4 + head] + aldv);
      if ((t & 31) == 0) se[head * 256 + j] = e;
      m = fmaxf(m, e);
    }
    __syncthreads();
    for (int j = 0; j < deg; ++j) {
      float w = __expf(se[head * 256 + j] - m);
      den += w;
      num = fmaf(w, h1[sl[j] * HID + t], num);
    }
  } else {  // fallback, never hit for this graph size
    for (int j = 0; j < deg; ++j)
      m = fmaxf(m, lrelu(als[srcs[off0 + j] * 4 + head] + aldv));
    for (int j = 0; j < deg; ++j) {
      int s = srcs[off0 + j];
      float w = __expf(lrelu(als[s * 4 + head] + aldv) - m);
      den += w;
      num = fmaf(w, h1[s * HID + t], num);
    }
  }
  out1[n * HID + t] = fmaxf(num / den + b1[t], 0.f);   // + bias, ReLU
}

// ---------- layer-2 softmax + aggregate + log_softmax: one wave per node ----------
__global__ __launch_bounds__(64) void k_agg2(const float* __restrict__ h2, const float* __restrict__ als,
                                             const float* __restrict__ ald, const int* __restrict__ offs,
                                             const int* __restrict__ srcs, const float* __restrict__ b2,
                                             float* __restrict__ out) {
  __shared__ int sl[256];
  __shared__ float se[256];
  int n = blockIdx.x, t = threadIdx.x;
  int off0 = offs[n], deg = offs[n + 1] - off0;
  float aldv = ald[n];
  float den = 0.f, num = 0.f, m;
  if (deg <= 256) {
    float lm = -INFINITY;
    for (int j = t; j < deg; j += 64) {
      int s = srcs[off0 + j];
      sl[j] = s;
      float e = lrelu(als[s] + aldv);
      se[j] = e;
      lm = fmaxf(lm, e);
    }
    #pragma unroll
    for (int o = 32; o >= 1; o >>= 1) lm = fmaxf(lm, __shfl_xor(lm, o));
    m = lm;
    __syncthreads();
    for (int j = 0; j < deg; ++j) {
      float w = __expf(se[j] - m);
      den += w;
      num = fmaf(w, h2[sl[j] * ODIM + t], num);
    }
  } else {
    float lm = -INFINITY;
    for (int j = 0; j < deg; ++j) lm = fmaxf(lm, lrelu(als[srcs[off0 + j]] + aldv));
    m = lm;
    for (int j = 0; j < deg; ++j) {
      int s = srcs[off0 + j];
      float w = __expf(lrelu(als[s] + aldv) - m);
      den += w;
      num = fmaf(w, h2[s * ODIM + t], num);
    }
  }
  float val = num / den + b2[t];
  // log_softmax over the 64 lanes
  float mx = val;
  #pragma unroll
  for (int o = 32; o >= 1; o >>= 1) mx = fmaxf(mx, __shfl_xor(mx, o));
  float ex = __expf(val - mx);
  float sum = ex;
  #pragma unroll
  for (int o = 32; o >= 1; o >>= 1) sum += __shfl_xor(sum, o);
  out[n * ODIM + t] = (val - mx) - __logf(sum);
}

extern "C" void kernel_launch(void* const* d_in, const int* in_sizes, int n_in,
                              void* d_out, int out_size, void* d_ws, size_t ws_size,
                              hipStream_t stream) {
  const float* x   = (const float*)d_in[0];
  const void*  ei  = d_in[1];
  const float* W1  = (const float*)d_in[2];
  const float* as1 = (const float*)d_in[3];
  const float* ad1 = (const float*)d_in[4];
  const float* b1  = (const float*)d_in[5];
  const float* W2  = (const float*)d_in[6];
  const float* as2 = (const float*)d_in[7];
  const float* ad2 = (const float*)d_in[8];
  const float* b2  = (const float*)d_in[9];
  float* out = (float*)d_out;

  char* ws = (char*)d_ws;
  size_t o = 0;
  auto alloc = [&](size_t bytes) { void* p = (void*)(ws + o); o += (bytes + 255) & ~(size_t)255; return p; };
  float* h1   = (float*)alloc((size_t)N_NODES * HID * 4);
  float* out1 = (float*)alloc((size_t)N_NODES * HID * 4);
  float* h2   = (float*)alloc((size_t)N_NODES * ODIM * 4);
  float* als1 = (float*)alloc((size_t)N_NODES * 4 * 4);
  float* ald1 = (float*)alloc((size_t)N_NODES * 4 * 4);
  float* als2 = (float*)alloc((size_t)N_NODES * 4);
  float* ald2 = (float*)alloc((size_t)N_NODES * 4);
  int*   deg  = (int*)alloc((size_t)N_NODES * 4);
  int*   offs = (int*)alloc((size_t)(N_NODES + 1) * 4);
  int*   cur  = (int*)alloc((size_t)N_NODES * 4);
  int*   srcs = (int*)alloc((size_t)E_TOT * 4);
  int*   bsums= (int*)alloc((size_t)NB1 * 4);
  int*   flag = (int*)alloc(4);

  hipMemsetAsync(deg, 0, (size_t)N_NODES * 4, stream);
  hipMemsetAsync(cur, 0, (size_t)N_NODES * 4, stream);
  k_detect<<<1, 64, 0, stream>>>(ei, flag);

  int egrid = (E_TOT + 255) / 256;
  k_hist   <<<egrid, 256, 0, stream>>>(ei, flag, deg);
  k_scan1  <<<NB1,   256, 0, stream>>>(deg, offs, bsums);
  k_scan2  <<<1,     256, 0, stream>>>(bsums);
  k_scan3  <<<NB1,   256, 0, stream>>>(offs, bsums);
  k_scatter<<<egrid, 256, 0, stream>>>(ei, flag, offs, cur, srcs);

  k_gemm1<<<1024, 256, 0, stream>>>(x, W1, h1);
  k_al1  <<<N_NODES / 2, 256, 0, stream>>>(h1, as1, ad1, als1, ald1);
  k_agg1 <<<N_NODES, 128, 0, stream>>>(h1, als1, ald1, offs, srcs, b1, out1);

  k_gemm2<<<1024, 256, 0, stream>>>(out1, W2, h2);
  k_al2  <<<N_NODES / 4, 256, 0, stream>>>(h2, as2, ad2, als2, ald2);
  k_agg2 <<<N_NODES, 64, 0, stream>>>(h2, als2, ald2, offs, srcs, b2, out);
}

// Round 2
// 323.151 us; speedup vs baseline: 1.1923x; 1.1923x over previous
//
#include <hip/hip_runtime.h>
#include <math.h>

#define N_NODES 50000
#define N_EDGES 800000
#define E_TOT   (N_EDGES + N_NODES)
#define IN_DIM  128
#define HID     128      // HEADS*HIDDEN (layer-1 output width)
#define ODIM    64
#define NEG     0.2f
#define NB1     ((N_NODES + 255) / 256)   // scan blocks = 196

__device__ __forceinline__ float lrelu(float x) { return x >= 0.f ? x : NEG * x; }

// bf16 <-> f32 helpers (RNE rounding on store)
__device__ __forceinline__ unsigned short f2b(float v) {
  unsigned int b = __float_as_uint(v);
  b += 0x7fffu + ((b >> 16) & 1u);
  return (unsigned short)(b >> 16);
}
__device__ __forceinline__ float b2f(unsigned short u) {
  return __uint_as_float(((unsigned int)u) << 16);
}

// ---------- edge-index dtype detection (int32 vs int64) ----------
__global__ void k_detect(const void* ei, int* flag) {
  if (threadIdx.x == 0 && blockIdx.x == 0) {
    const int* p = (const int*)ei;
    int allz = 1;
    for (int i = 0; i < 64; ++i) if (p[2 * i + 1] != 0) { allz = 0; break; }
    *flag = allz;  // 1 => buffer is int64
  }
}

__device__ __forceinline__ int e_src(const void* ei, int f, int e) {
  if (e >= N_EDGES) return e - N_EDGES;              // self loop
  return f ? (int)((const long long*)ei)[e] : ((const int*)ei)[e];
}
__device__ __forceinline__ int e_dst(const void* ei, int f, int e) {
  if (e >= N_EDGES) return e - N_EDGES;              // self loop
  return f ? (int)((const long long*)ei)[N_EDGES + e] : ((const int*)ei)[N_EDGES + e];
}

// ---------- CSR build ----------
__global__ void k_hist(const void* ei, const int* flag, int* deg) {
  int e = blockIdx.x * 256 + threadIdx.x;
  if (e >= E_TOT) return;
  atomicAdd(&deg[e_dst(ei, *flag, e)], 1);
}

__global__ void k_scan1(const int* __restrict__ deg, int* __restrict__ offs, int* __restrict__ bsums) {
  __shared__ int sm[256];
  int t = threadIdx.x, i = blockIdx.x * 256 + t;
  int v = (i < N_NODES) ? deg[i] : 0;
  sm[t] = v;
  __syncthreads();
  for (int o = 1; o < 256; o <<= 1) {
    int add = (t >= o) ? sm[t - o] : 0;
    __syncthreads();
    sm[t] += add;
    __syncthreads();
  }
  if (i < N_NODES) offs[i] = sm[t] - v;   // exclusive
  if (t == 255) bsums[blockIdx.x] = sm[255];
}

__global__ void k_scan2(int* bsums) {
  __shared__ int sm[256];
  int t = threadIdx.x;
  int v = (t < NB1) ? bsums[t] : 0;
  sm[t] = v;
  __syncthreads();
  for (int o = 1; o < 256; o <<= 1) {
    int add = (t >= o) ? sm[t - o] : 0;
    __syncthreads();
    sm[t] += add;
    __syncthreads();
  }
  if (t < NB1) bsums[t] = sm[t] - v;      // exclusive
}

__global__ void k_scan3(int* __restrict__ offs, const int* __restrict__ bsums) {
  int i = blockIdx.x * 256 + threadIdx.x;
  if (i < N_NODES) offs[i] += bsums[blockIdx.x];
  if (i == 0) offs[N_NODES] = E_TOT;
}

__global__ void k_scatter(const void* ei, const int* __restrict__ flag, const int* __restrict__ offs,
                          int* __restrict__ cur, int* __restrict__ srcs) {
  int e = blockIdx.x * 256 + threadIdx.x;
  if (e >= E_TOT) return;
  int f = *flag;
  int d = e_dst(ei, f, e);
  int pos = offs[d] + atomicAdd(&cur[d], 1);
  srcs[pos] = e_src(ei, f, e);
}

// ---------- GEMM1: h1b[N,128](bf16) = x[N,128] @ W1[128,128] ----------
__global__ __launch_bounds__(256) void k_gemm1(const float* __restrict__ x, const float* __restrict__ W,
                                               unsigned short* __restrict__ h1b) {
  __shared__ float Wl[64 * HID];     // 32 KB (rows kb..kb+63)
  __shared__ float xs[8 * IN_DIM];   // 4 KB
  int t = threadIdx.x, col = t & 127, ng = t >> 7;
  for (int chunk = blockIdx.x; chunk < N_NODES / 8; chunk += gridDim.x) {
    int base = chunk * 8;
    __syncthreads();
    for (int i = t; i < 8 * IN_DIM; i += 256) xs[i] = x[base * IN_DIM + i];
    float a0 = 0, a1 = 0, a2 = 0, a3 = 0;
    for (int kb = 0; kb < IN_DIM; kb += 64) {
      __syncthreads();
      for (int i = t; i < 64 * HID; i += 256) Wl[i] = W[kb * HID + i];
      __syncthreads();
      #pragma unroll 8
      for (int kk = 0; kk < 64; ++kk) {
        int k = kb + kk;
        float w = Wl[kk * HID + col];
        a0 = fmaf(xs[(ng + 0) * IN_DIM + k], w, a0);
        a1 = fmaf(xs[(ng + 2) * IN_DIM + k], w, a1);
        a2 = fmaf(xs[(ng + 4) * IN_DIM + k], w, a2);
        a3 = fmaf(xs[(ng + 6) * IN_DIM + k], w, a3);
      }
    }
    h1b[(base + ng + 0) * HID + col] = f2b(a0);
    h1b[(base + ng + 2) * HID + col] = f2b(a1);
    h1b[(base + ng + 4) * HID + col] = f2b(a2);
    h1b[(base + ng + 6) * HID + col] = f2b(a3);
  }
}

// ---------- GEMM2: h2b[N,64](bf16) = out1[N,128] @ W2[128,64] ----------
__global__ __launch_bounds__(256) void k_gemm2(const float* __restrict__ x, const float* __restrict__ W,
                                               unsigned short* __restrict__ h2b) {
  __shared__ float Wl[HID * ODIM];   // 32 KB, staged once
  __shared__ float xs[16 * HID];     // 8 KB
  int t = threadIdx.x, col = t & 63, ng = t >> 6;   // ng 0..3
  for (int i = t; i < HID * ODIM; i += 256) Wl[i] = W[i];
  for (int chunk = blockIdx.x; chunk < N_NODES / 16; chunk += gridDim.x) {
    int base = chunk * 16;
    __syncthreads();
    for (int i = t; i < 16 * HID; i += 256) xs[i] = x[base * HID + i];
    __syncthreads();
    float a0 = 0, a1 = 0, a2 = 0, a3 = 0;
    #pragma unroll 8
    for (int k = 0; k < HID; ++k) {
      float w = Wl[k * ODIM + col];
      a0 = fmaf(xs[(ng +  0) * HID + k], w, a0);
      a1 = fmaf(xs[(ng +  4) * HID + k], w, a1);
      a2 = fmaf(xs[(ng +  8) * HID + k], w, a2);
      a3 = fmaf(xs[(ng + 12) * HID + k], w, a3);
    }
    h2b[(base + ng +  0) * ODIM + col] = f2b(a0);
    h2b[(base + ng +  4) * ODIM + col] = f2b(a1);
    h2b[(base + ng +  8) * ODIM + col] = f2b(a2);
    h2b[(base + ng + 12) * ODIM + col] = f2b(a3);
  }
}

// ---------- attention logits ----------
__global__ __launch_bounds__(256) void k_al1(const unsigned short* __restrict__ h1b,
                                             const float* __restrict__ asrc,
                                             const float* __restrict__ adst, float* __restrict__ als,
                                             float* __restrict__ ald) {
  int t = threadIdx.x;
  int n = blockIdx.x * 2 + (t >> 7);
  int col = t & 127;
  float v = b2f(h1b[n * HID + col]);
  float s = v * asrc[col], d = v * adst[col];   // a_src1 flat [4*32]
  #pragma unroll
  for (int o = 16; o >= 1; o >>= 1) { s += __shfl_xor(s, o); d += __shfl_xor(d, o); }
  if ((col & 31) == 0) { als[n * 4 + (col >> 5)] = s; ald[n * 4 + (col >> 5)] = d; }
}

__global__ __launch_bounds__(256) void k_al2(const unsigned short* __restrict__ h2b,
                                             const float* __restrict__ asrc,
                                             const float* __restrict__ adst, float* __restrict__ als,
                                             float* __restrict__ ald) {
  int t = threadIdx.x;
  int n = blockIdx.x * 4 + (t >> 6);
  int col = t & 63;
  float v = b2f(h2b[n * ODIM + col]);
  float s = v * asrc[col], d = v * adst[col];
  #pragma unroll
  for (int o = 32; o >= 1; o >>= 1) { s += __shfl_xor(s, o); d += __shfl_xor(d, o); }
  if (col == 0) { als[n] = s; ald[n] = d; }
}

// ---------- layer-1 softmax + aggregate: one block (128 thr) per dst node ----------
__global__ __launch_bounds__(128) void k_agg1(const unsigned short* __restrict__ h1b,
                                              const float* __restrict__ als,
                                              const float* __restrict__ ald, const int* __restrict__ offs,
                                              const int* __restrict__ srcs, const float* __restrict__ b1,
                                              float* __restrict__ out1) {
  __shared__ int sl[256];
  __shared__ float sw[4 * 256];
  __shared__ float redm[2][4];
  __shared__ float redd[2][4];
  int n = blockIdx.x, t = threadIdx.x;
  int head = t >> 5, wave = t >> 6, lane = t & 63;
  int off0 = offs[n], deg = offs[n + 1] - off0;

  if (deg <= 256) {
    const float4* als4 = (const float4*)als;
    float4 ad = ((const float4*)ald)[n];
    // pass A: edge-parallel logits + local max (all 4 heads per thread)
    float lm0 = -INFINITY, lm1 = -INFINITY, lm2 = -INFINITY, lm3 = -INFINITY;
    for (int j = t; j < deg; j += 128) {
      int s = srcs[off0 + j];
      sl[j] = s;
      float4 a = als4[s];
      float e0 = lrelu(a.x + ad.x), e1 = lrelu(a.y + ad.y);
      float e2 = lrelu(a.z + ad.z), e3 = lrelu(a.w + ad.w);
      sw[0 * 256 + j] = e0; sw[1 * 256 + j] = e1;
      sw[2 * 256 + j] = e2; sw[3 * 256 + j] = e3;
      lm0 = fmaxf(lm0, e0); lm1 = fmaxf(lm1, e1);
      lm2 = fmaxf(lm2, e2); lm3 = fmaxf(lm3, e3);
    }
    #pragma unroll
    for (int o = 32; o >= 1; o >>= 1) {
      lm0 = fmaxf(lm0, __shfl_xor(lm0, o)); lm1 = fmaxf(lm1, __shfl_xor(lm1, o));
      lm2 = fmaxf(lm2, __shfl_xor(lm2, o)); lm3 = fmaxf(lm3, __shfl_xor(lm3, o));
    }
    if (lane == 0) { redm[wave][0] = lm0; redm[wave][1] = lm1; redm[wave][2] = lm2; redm[wave][3] = lm3; }
    __syncthreads();
    float m0 = fmaxf(redm[0][0], redm[1][0]), m1 = fmaxf(redm[0][1], redm[1][1]);
    float m2 = fmaxf(redm[0][2], redm[1][2]), m3 = fmaxf(redm[0][3], redm[1][3]);
    // pass B: edge-parallel exp + local denom
    float d0 = 0.f, d1 = 0.f, d2 = 0.f, d3 = 0.f;
    for (int j = t; j < deg; j += 128) {
      float w0 = __expf(sw[0 * 256 + j] - m0); sw[0 * 256 + j] = w0; d0 += w0;
      float w1 = __expf(sw[1 * 256 + j] - m1); sw[1 * 256 + j] = w1; d1 += w1;
      float w2 = __expf(sw[2 * 256 + j] - m2); sw[2 * 256 + j] = w2; d2 += w2;
      float w3 = __expf(sw[3 * 256 + j] - m3); sw[3 * 256 + j] = w3; d3 += w3;
    }
    #pragma unroll
    for (int o = 32; o >= 1; o >>= 1) {
      d0 += __shfl_xor(d0, o); d1 += __shfl_xor(d1, o);
      d2 += __shfl_xor(d2, o); d3 += __shfl_xor(d3, o);
    }
    if (lane == 0) { redd[wave][0] = d0; redd[wave][1] = d1; redd[wave][2] = d2; redd[wave][3] = d3; }
    __syncthreads();
    float den4[4];
    den4[0] = redd[0][0] + redd[1][0]; den4[1] = redd[0][1] + redd[1][1];
    den4[2] = redd[0][2] + redd[1][2]; den4[3] = redd[0][3] + redd[1][3];
    float den = den4[head];
    // pass C: gather, unroll x4 for MLP
    const float* swh = &sw[head * 256];
    float num = 0.f;
    int j = 0;
    for (; j + 4 <= deg; j += 4) {
      int s0 = sl[j], s1 = sl[j + 1], s2 = sl[j + 2], s3 = sl[j + 3];
      float v0 = b2f(h1b[s0 * HID + t]);
      float v1 = b2f(h1b[s1 * HID + t]);
      float v2 = b2f(h1b[s2 * HID + t]);
      float v3 = b2f(h1b[s3 * HID + t]);
      num = fmaf(swh[j],     v0, num);
      num = fmaf(swh[j + 1], v1, num);
      num = fmaf(swh[j + 2], v2, num);
      num = fmaf(swh[j + 3], v3, num);
    }
    for (; j < deg; ++j) num = fmaf(swh[j], b2f(h1b[sl[j] * HID + t]), num);
    out1[n * HID + t] = fmaxf(num / den + b1[t], 0.f);
  } else {  // fallback (not hit at this graph size)
    float aldv = ald[n * 4 + head];
    float m = -INFINITY, den = 0.f, num = 0.f;
    for (int j = 0; j < deg; ++j)
      m = fmaxf(m, lrelu(als[srcs[off0 + j] * 4 + head] + aldv));
    for (int j = 0; j < deg; ++j) {
      int s = srcs[off0 + j];
      float w = __expf(lrelu(als[s * 4 + head] + aldv) - m);
      den += w;
      num = fmaf(w, b2f(h1b[s * HID + t]), num);
    }
    out1[n * HID + t] = fmaxf(num / den + b1[t], 0.f);
  }
}

// ---------- layer-2 softmax + aggregate + log_softmax: one wave per node ----------
__global__ __launch_bounds__(64) void k_agg2(const unsigned short* __restrict__ h2b,
                                             const float* __restrict__ als,
                                             const float* __restrict__ ald, const int* __restrict__ offs,
                                             const int* __restrict__ srcs, const float* __restrict__ b2,
                                             float* __restrict__ out) {
  __shared__ int sl[256];
  __shared__ float sw[256];
  int n = blockIdx.x, t = threadIdx.x;
  int off0 = offs[n], deg = offs[n + 1] - off0;
  float aldv = ald[n];
  float den = 0.f, num = 0.f;
  if (deg <= 256) {
    float lm = -INFINITY;
    for (int j = t; j < deg; j += 64) {
      int s = srcs[off0 + j];
      sl[j] = s;
      float e = lrelu(als[s] + aldv);
      sw[j] = e;
      lm = fmaxf(lm, e);
    }
    #pragma unroll
    for (int o = 32; o >= 1; o >>= 1) lm = fmaxf(lm, __shfl_xor(lm, o));
    __syncthreads();
    float ld = 0.f;
    for (int j = t; j < deg; j += 64) {
      float w = __expf(sw[j] - lm);
      sw[j] = w;
      ld += w;
    }
    #pragma unroll
    for (int o = 32; o >= 1; o >>= 1) ld += __shfl_xor(ld, o);
    den = ld;
    __syncthreads();
    int j = 0;
    for (; j + 4 <= deg; j += 4) {
      int s0 = sl[j], s1 = sl[j + 1], s2 = sl[j + 2], s3 = sl[j + 3];
      float v0 = b2f(h2b[s0 * ODIM + t]);
      float v1 = b2f(h2b[s1 * ODIM + t]);
      float v2 = b2f(h2b[s2 * ODIM + t]);
      float v3 = b2f(h2b[s3 * ODIM + t]);
      num = fmaf(sw[j],     v0, num);
      num = fmaf(sw[j + 1], v1, num);
      num = fmaf(sw[j + 2], v2, num);
      num = fmaf(sw[j + 3], v3, num);
    }
    for (; j < deg; ++j) num = fmaf(sw[j], b2f(h2b[sl[j] * ODIM + t]), num);
  } else {
    float lm = -INFINITY;
    for (int j = 0; j < deg; ++j) lm = fmaxf(lm, lrelu(als[srcs[off0 + j]] + aldv));
    for (int j = 0; j < deg; ++j) {
      int s = srcs[off0 + j];
      float w = __expf(lrelu(als[s] + aldv) - lm);
      den += w;
      num = fmaf(w, b2f(h2b[s * ODIM + t]), num);
    }
  }
  float val = num / den + b2[t];
  // log_softmax over the 64 lanes
  float mx = val;
  #pragma unroll
  for (int o = 32; o >= 1; o >>= 1) mx = fmaxf(mx, __shfl_xor(mx, o));
  float ex = __expf(val - mx);
  float sum = ex;
  #pragma unroll
  for (int o = 32; o >= 1; o >>= 1) sum += __shfl_xor(sum, o);
  out[n * ODIM + t] = (val - mx) - __logf(sum);
}

extern "C" void kernel_launch(void* const* d_in, const int* in_sizes, int n_in,
                              void* d_out, int out_size, void* d_ws, size_t ws_size,
                              hipStream_t stream) {
  const float* x   = (const float*)d_in[0];
  const void*  ei  = d_in[1];
  const float* W1  = (const float*)d_in[2];
  const float* as1 = (const float*)d_in[3];
  const float* ad1 = (const float*)d_in[4];
  const float* b1  = (const float*)d_in[5];
  const float* W2  = (const float*)d_in[6];
  const float* as2 = (const float*)d_in[7];
  const float* ad2 = (const float*)d_in[8];
  const float* b2  = (const float*)d_in[9];
  float* out = (float*)d_out;

  char* ws = (char*)d_ws;
  size_t o = 0;
  auto alloc = [&](size_t bytes) { void* p = (void*)(ws + o); o += (bytes + 255) & ~(size_t)255; return p; };
  unsigned short* h1b  = (unsigned short*)alloc((size_t)N_NODES * HID * 2);
  float*          out1 = (float*)alloc((size_t)N_NODES * HID * 4);
  unsigned short* h2b  = (unsigned short*)alloc((size_t)N_NODES * ODIM * 2);
  float* als1 = (float*)alloc((size_t)N_NODES * 4 * 4);
  float* ald1 = (float*)alloc((size_t)N_NODES * 4 * 4);
  float* als2 = (float*)alloc((size_t)N_NODES * 4);
  float* ald2 = (float*)alloc((size_t)N_NODES * 4);
  int*   deg  = (int*)alloc((size_t)N_NODES * 4);
  int*   offs = (int*)alloc((size_t)(N_NODES + 1) * 4);
  int*   cur  = (int*)alloc((size_t)N_NODES * 4);
  int*   srcs = (int*)alloc((size_t)E_TOT * 4);
  int*   bsums= (int*)alloc((size_t)NB1 * 4);
  int*   flag = (int*)alloc(4);

  hipMemsetAsync(deg, 0, (size_t)N_NODES * 4, stream);
  hipMemsetAsync(cur, 0, (size_t)N_NODES * 4, stream);
  k_detect<<<1, 64, 0, stream>>>(ei, flag);

  int egrid = (E_TOT + 255) / 256;
  k_hist   <<<egrid, 256, 0, stream>>>(ei, flag, deg);
  k_scan1  <<<NB1,   256, 0, stream>>>(deg, offs, bsums);
  k_scan2  <<<1,     256, 0, stream>>>(bsums);
  k_scan3  <<<NB1,   256, 0, stream>>>(offs, bsums);
  k_scatter<<<egrid, 256, 0, stream>>>(ei, flag, offs, cur, srcs);

  k_gemm1<<<1024, 256, 0, stream>>>(x, W1, h1b);
  k_al1  <<<N_NODES / 2, 256, 0, stream>>>(h1b, as1, ad1, als1, ald1);
  k_agg1 <<<N_NODES, 128, 0, stream>>>(h1b, als1, ald1, offs, srcs, b1, out1);

  k_gemm2<<<1024, 256, 0, stream>>>(out1, W2, h2b);
  k_al2  <<<N_NODES / 4, 256, 0, stream>>>(h2b, as2, ad2, als2, ald2);
  k_agg2 <<<N_NODES, 64, 0, stream>>>(h2b, als2, ald2, offs, srcs, b2, out);
}

// Round 3
// 240.901 us; speedup vs baseline: 1.5994x; 1.3414x over previous
//
#include <hip/hip_runtime.h>
#include <hip/hip_bf16.h>
#include <math.h>

#define N_NODES 50000
#define N_EDGES 800000
#define E_TOT   (N_EDGES + N_NODES)
#define IN_DIM  128
#define HID     128      // HEADS*HIDDEN (layer-1 output width)
#define ODIM    64
#define NEG     0.2f
#define NB1     ((N_NODES + 255) / 256)   // scan blocks = 196
#define NCHUNK  ((N_NODES + 31) / 32)     // 1563 32-node chunks

typedef short bf16x8 __attribute__((ext_vector_type(8)));
typedef float f32x4 __attribute__((ext_vector_type(4)));
typedef unsigned short ushort_t;

__device__ __forceinline__ float lrelu(float x) { return x >= 0.f ? x : NEG * x; }

// bf16 <-> f32 helpers (RNE rounding on store)
__device__ __forceinline__ unsigned short f2b(float v) {
  unsigned int b = __float_as_uint(v);
  b += 0x7fffu + ((b >> 16) & 1u);
  return (unsigned short)(b >> 16);
}
__device__ __forceinline__ float b2f(unsigned short u) {
  return __uint_as_float(((unsigned int)u) << 16);
}
__device__ __forceinline__ unsigned int f2b2(float lo, float hi) {
  union { __hip_bfloat162 h; unsigned int u; } cv;
  cv.h = __float22bfloat162_rn(make_float2(lo, hi));
  return cv.u;
}

// ---------- edge-index dtype detection (int32 vs int64) ----------
__global__ void k_detect(const void* ei, int* flag) {
  if (threadIdx.x == 0 && blockIdx.x == 0) {
    const int* p = (const int*)ei;
    int allz = 1;
    for (int i = 0; i < 64; ++i) if (p[2 * i + 1] != 0) { allz = 0; break; }
    *flag = allz;  // 1 => buffer is int64
  }
}

__device__ __forceinline__ int e_src(const void* ei, int f, int e) {
  if (e >= N_EDGES) return e - N_EDGES;              // self loop
  return f ? (int)((const long long*)ei)[e] : ((const int*)ei)[e];
}
__device__ __forceinline__ int e_dst(const void* ei, int f, int e) {
  if (e >= N_EDGES) return e - N_EDGES;              // self loop
  return f ? (int)((const long long*)ei)[N_EDGES + e] : ((const int*)ei)[N_EDGES + e];
}

// ---------- CSR build ----------
__global__ void k_hist(const void* ei, const int* flag, int* deg) {
  int e = blockIdx.x * 256 + threadIdx.x;
  if (e >= E_TOT) return;
  atomicAdd(&deg[e_dst(ei, *flag, e)], 1);
}

__global__ void k_scan1(const int* __restrict__ deg, int* __restrict__ offs, int* __restrict__ bsums) {
  __shared__ int sm[256];
  int t = threadIdx.x, i = blockIdx.x * 256 + t;
  int v = (i < N_NODES) ? deg[i] : 0;
  sm[t] = v;
  __syncthreads();
  for (int o = 1; o < 256; o <<= 1) {
    int add = (t >= o) ? sm[t - o] : 0;
    __syncthreads();
    sm[t] += add;
    __syncthreads();
  }
  if (i < N_NODES) offs[i] = sm[t] - v;   // exclusive
  if (t == 255) bsums[blockIdx.x] = sm[255];
}

__global__ void k_scan2(int* bsums) {
  __shared__ int sm[256];
  int t = threadIdx.x;
  int v = (t < NB1) ? bsums[t] : 0;
  sm[t] = v;
  __syncthreads();
  for (int o = 1; o < 256; o <<= 1) {
    int add = (t >= o) ? sm[t - o] : 0;
    __syncthreads();
    sm[t] += add;
    __syncthreads();
  }
  if (t < NB1) bsums[t] = sm[t] - v;      // exclusive
}

__global__ void k_scan3(int* __restrict__ offs, const int* __restrict__ bsums) {
  int i = blockIdx.x * 256 + threadIdx.x;
  if (i < N_NODES) offs[i] += bsums[blockIdx.x];
  if (i == 0) offs[N_NODES] = E_TOT;
}

__global__ void k_scatter(const void* ei, const int* __restrict__ flag, const int* __restrict__ offs,
                          int* __restrict__ cur, int* __restrict__ srcs) {
  int e = blockIdx.x * 256 + threadIdx.x;
  if (e >= E_TOT) return;
  int f = *flag;
  int d = e_dst(ei, f, e);
  int pos = offs[d] + atomicAdd(&cur[d], 1);
  srcs[pos] = e_src(ei, f, e);
}

// ---------- weight prep: bf16 W^T for both layers ----------
__global__ void k_prep(const float* __restrict__ W1, const float* __restrict__ W2,
                       ushort_t* __restrict__ Wt1, ushort_t* __restrict__ Wt2) {
  int i = blockIdx.x * 256 + threadIdx.x;
  if (i < 128 * 128) { int k = i >> 7, n = i & 127; Wt1[n * 128 + k] = f2b(W1[i]); }
  if (i < 128 * 64)  { int k = i >> 6, n = i & 63;  Wt2[n * 128 + k] = f2b(W2[i]); }
}

// ---------- MFMA GEMM1: h1b[N,128](bf16) = bf16(x[N,128]) @ W1 ----------
// block = 256 thr (4 waves), 32 nodes/chunk, LDS xs[32][128] bf16 XOR-swizzled.
// Fragment layout (m91/m92-verified convention):
//   A lane l: row = l&15, k = (l>>4)*8 + i  (contiguous 16B from xs row)
//   B lane l: col = l&15, k = (l>>4)*8 + i  (contiguous 16B from W^T row)
//   D lane l, reg r: row = (l>>4)*4 + r, col = l&15
__global__ __launch_bounds__(256) void k_mm1(const float* __restrict__ x,
                                             const ushort_t* __restrict__ Wt,
                                             ushort_t* __restrict__ h1b) {
  __shared__ ushort_t xs[32 * 128];   // 8 KB
  int t = threadIdx.x;
  int w = t >> 6, l = t & 63;
  int lr = l & 15, lk = l >> 4;
  int nodeSub = (w & 1) * 16, colBase = (w >> 1) * 64;
  // B fragments: 4 col-tiles x 4 k-steps, held in registers for the whole kernel
  bf16x8 bfrag[4][4];
  #pragma unroll
  for (int ct = 0; ct < 4; ++ct)
    #pragma unroll
    for (int ks = 0; ks < 4; ++ks) {
      int n = colBase + ct * 16 + lr;
      int k = ks * 32 + lk * 8;
      bfrag[ct][ks] = *(const bf16x8*)&Wt[n * 128 + k];
    }
  int rr = t >> 3, c0 = (t & 7) * 16;   // staging: row, 16-elem col group
  for (int chunk = blockIdx.x; chunk < NCHUNK; chunk += gridDim.x) {
    int base = chunk * 32;
    int srcRow = base + rr; if (srcRow >= N_NODES) srcRow = N_NODES - 1;
    const float4* xr = (const float4*)&x[(size_t)srcRow * IN_DIM + c0];
    float4 f0 = xr[0], f1 = xr[1], f2 = xr[2], f3 = xr[3];
    uint4 w0, w1;
    w0.x = f2b2(f0.x, f0.y); w0.y = f2b2(f0.z, f0.w);
    w0.z = f2b2(f1.x, f1.y); w0.w = f2b2(f1.z, f1.w);
    w1.x = f2b2(f2.x, f2.y); w1.y = f2b2(f2.z, f2.w);
    w1.z = f2b2(f3.x, f3.y); w1.w = f2b2(f3.z, f3.w);
    char* xsb = (char*)xs;
    int swz = (rr & 7) << 4;
    *(uint4*)(xsb + rr * 256 + ((c0 * 2 +  0) ^ swz)) = w0;
    *(uint4*)(xsb + rr * 256 + ((c0 * 2 + 16) ^ swz)) = w1;
    __syncthreads();
    f32x4 acc[4] = {{0,0,0,0},{0,0,0,0},{0,0,0,0},{0,0,0,0}};
    int arow = nodeSub + lr;
    #pragma unroll
    for (int ks = 0; ks < 4; ++ks) {
      bf16x8 a = *(const bf16x8*)((const char*)xs + arow * 256 +
                                  ((ks * 64 + lk * 16) ^ ((arow & 7) << 4)));
      #pragma unroll
      for (int ct = 0; ct < 4; ++ct)
        acc[ct] = __builtin_amdgcn_mfma_f32_16x16x32_bf16(a, bfrag[ct][ks], acc[ct], 0, 0, 0);
    }
    __syncthreads();
    #pragma unroll
    for (int ct = 0; ct < 4; ++ct)
      #pragma unroll
      for (int r = 0; r < 4; ++r) {
        int node = base + nodeSub + lk * 4 + r;
        if (node < N_NODES)
          h1b[(size_t)node * HID + colBase + ct * 16 + lr] = f2b(acc[ct][r]);
      }
  }
}

// ---------- MFMA GEMM2: h2b[N,64](bf16) = out1b[N,128] @ W2 ----------
__global__ __launch_bounds__(256) void k_mm2(const ushort_t* __restrict__ xb,
                                             const ushort_t* __restrict__ Wt,
                                             ushort_t* __restrict__ h2b) {
  __shared__ ushort_t xs[32 * 128];   // 8 KB
  int t = threadIdx.x;
  int w = t >> 6, l = t & 63;
  int lr = l & 15, lk = l >> 4;
  int nodeSub = (w & 1) * 16, colBase = (w >> 1) * 32;
  bf16x8 bfrag[2][4];
  #pragma unroll
  for (int ct = 0; ct < 2; ++ct)
    #pragma unroll
    for (int ks = 0; ks < 4; ++ks) {
      int n = colBase + ct * 16 + lr;
      int k = ks * 32 + lk * 8;
      bfrag[ct][ks] = *(const bf16x8*)&Wt[n * 128 + k];
    }
  int rr = t >> 3, c0 = (t & 7) * 16;
  for (int chunk = blockIdx.x; chunk < NCHUNK; chunk += gridDim.x) {
    int base = chunk * 32;
    int srcRow = base + rr; if (srcRow >= N_NODES) srcRow = N_NODES - 1;
    const uint4* xr = (const uint4*)&xb[(size_t)srcRow * HID + c0];
    uint4 w0 = xr[0], w1 = xr[1];
    char* xsb = (char*)xs;
    int swz = (rr & 7) << 4;
    *(uint4*)(xsb + rr * 256 + ((c0 * 2 +  0) ^ swz)) = w0;
    *(uint4*)(xsb + rr * 256 + ((c0 * 2 + 16) ^ swz)) = w1;
    __syncthreads();
    f32x4 acc[2] = {{0,0,0,0},{0,0,0,0}};
    int arow = nodeSub + lr;
    #pragma unroll
    for (int ks = 0; ks < 4; ++ks) {
      bf16x8 a = *(const bf16x8*)((const char*)xs + arow * 256 +
                                  ((ks * 64 + lk * 16) ^ ((arow & 7) << 4)));
      #pragma unroll
      for (int ct = 0; ct < 2; ++ct)
        acc[ct] = __builtin_amdgcn_mfma_f32_16x16x32_bf16(a, bfrag[ct][ks], acc[ct], 0, 0, 0);
    }
    __syncthreads();
    #pragma unroll
    for (int ct = 0; ct < 2; ++ct)
      #pragma unroll
      for (int r = 0; r < 4; ++r) {
        int node = base + nodeSub + lk * 4 + r;
        if (node < N_NODES)
          h2b[(size_t)node * ODIM + colBase + ct * 16 + lr] = f2b(acc[ct][r]);
      }
  }
}

// ---------- attention logits ----------
__global__ __launch_bounds__(256) void k_al1(const ushort_t* __restrict__ h1b,
                                             const float* __restrict__ asrc,
                                             const float* __restrict__ adst, float* __restrict__ als,
                                             float* __restrict__ ald) {
  int t = threadIdx.x;
  int n = blockIdx.x * 2 + (t >> 7);
  int col = t & 127;
  float v = b2f(h1b[n * HID + col]);
  float s = v * asrc[col], d = v * adst[col];   // a_src1 flat [4*32]
  #pragma unroll
  for (int o = 16; o >= 1; o >>= 1) { s += __shfl_xor(s, o); d += __shfl_xor(d, o); }
  if ((col & 31) == 0) { als[n * 4 + (col >> 5)] = s; ald[n * 4 + (col >> 5)] = d; }
}

__global__ __launch_bounds__(256) void k_al2(const ushort_t* __restrict__ h2b,
                                             const float* __restrict__ asrc,
                                             const float* __restrict__ adst, float* __restrict__ als,
                                             float* __restrict__ ald) {
  int t = threadIdx.x;
  int n = blockIdx.x * 4 + (t >> 6);
  int col = t & 63;
  float v = b2f(h2b[n * ODIM + col]);
  float s = v * asrc[col], d = v * adst[col];
  #pragma unroll
  for (int o = 32; o >= 1; o >>= 1) { s += __shfl_xor(s, o); d += __shfl_xor(d, o); }
  if (col == 0) { als[n] = s; ald[n] = d; }
}

// ---------- layer-1 softmax + aggregate: one block (128 thr) per dst node ----------
__global__ __launch_bounds__(128) void k_agg1(const ushort_t* __restrict__ h1b,
                                              const float* __restrict__ als,
                                              const float* __restrict__ ald, const int* __restrict__ offs,
                                              const int* __restrict__ srcs, const float* __restrict__ b1,
                                              ushort_t* __restrict__ out1b) {
  __shared__ int sl[256];
  __shared__ float sw[4 * 256];
  __shared__ float redm[2][4];
  __shared__ float redd[2][4];
  int n = blockIdx.x, t = threadIdx.x;
  int head = t >> 5, wave = t >> 6, lane = t & 63;
  int off0 = offs[n], deg = offs[n + 1] - off0;

  if (deg <= 256) {
    const float4* als4 = (const float4*)als;
    float4 ad = ((const float4*)ald)[n];
    float lm0 = -INFINITY, lm1 = -INFINITY, lm2 = -INFINITY, lm3 = -INFINITY;
    for (int j = t; j < deg; j += 128) {
      int s = srcs[off0 + j];
      sl[j] = s;
      float4 a = als4[s];
      float e0 = lrelu(a.x + ad.x), e1 = lrelu(a.y + ad.y);
      float e2 = lrelu(a.z + ad.z), e3 = lrelu(a.w + ad.w);
      sw[0 * 256 + j] = e0; sw[1 * 256 + j] = e1;
      sw[2 * 256 + j] = e2; sw[3 * 256 + j] = e3;
      lm0 = fmaxf(lm0, e0); lm1 = fmaxf(lm1, e1);
      lm2 = fmaxf(lm2, e2); lm3 = fmaxf(lm3, e3);
    }
    #pragma unroll
    for (int o = 32; o >= 1; o >>= 1) {
      lm0 = fmaxf(lm0, __shfl_xor(lm0, o)); lm1 = fmaxf(lm1, __shfl_xor(lm1, o));
      lm2 = fmaxf(lm2, __shfl_xor(lm2, o)); lm3 = fmaxf(lm3, __shfl_xor(lm3, o));
    }
    if (lane == 0) { redm[wave][0] = lm0; redm[wave][1] = lm1; redm[wave][2] = lm2; redm[wave][3] = lm3; }
    __syncthreads();
    float m0 = fmaxf(redm[0][0], redm[1][0]), m1 = fmaxf(redm[0][1], redm[1][1]);
    float m2 = fmaxf(redm[0][2], redm[1][2]), m3 = fmaxf(redm[0][3], redm[1][3]);
    float d0 = 0.f, d1 = 0.f, d2 = 0.f, d3 = 0.f;
    for (int j = t; j < deg; j += 128) {
      float w0 = __expf(sw[0 * 256 + j] - m0); sw[0 * 256 + j] = w0; d0 += w0;
      float w1 = __expf(sw[1 * 256 + j] - m1); sw[1 * 256 + j] = w1; d1 += w1;
      float w2 = __expf(sw[2 * 256 + j] - m2); sw[2 * 256 + j] = w2; d2 += w2;
      float w3 = __expf(sw[3 * 256 + j] - m3); sw[3 * 256 + j] = w3; d3 += w3;
    }
    #pragma unroll
    for (int o = 32; o >= 1; o >>= 1) {
      d0 += __shfl_xor(d0, o); d1 += __shfl_xor(d1, o);
      d2 += __shfl_xor(d2, o); d3 += __shfl_xor(d3, o);
    }
    if (lane == 0) { redd[wave][0] = d0; redd[wave][1] = d1; redd[wave][2] = d2; redd[wave][3] = d3; }
    __syncthreads();
    float den4[4];
    den4[0] = redd[0][0] + redd[1][0]; den4[1] = redd[0][1] + redd[1][1];
    den4[2] = redd[0][2] + redd[1][2]; den4[3] = redd[0][3] + redd[1][3];
    float den = den4[head];
    const float* swh = &sw[head * 256];
    float num = 0.f;
    int j = 0;
    for (; j + 4 <= deg; j += 4) {
      int s0 = sl[j], s1 = sl[j + 1], s2 = sl[j + 2], s3 = sl[j + 3];
      float v0 = b2f(h1b[s0 * HID + t]);
      float v1 = b2f(h1b[s1 * HID + t]);
      float v2 = b2f(h1b[s2 * HID + t]);
      float v3 = b2f(h1b[s3 * HID + t]);
      num = fmaf(swh[j],     v0, num);
      num = fmaf(swh[j + 1], v1, num);
      num = fmaf(swh[j + 2], v2, num);
      num = fmaf(swh[j + 3], v3, num);
    }
    for (; j < deg; ++j) num = fmaf(swh[j], b2f(h1b[sl[j] * HID + t]), num);
    out1b[n * HID + t] = f2b(fmaxf(num / den + b1[t], 0.f));
  } else {  // fallback (not hit at this graph size)
    float aldv = ald[n * 4 + head];
    float m = -INFINITY, den = 0.f, num = 0.f;
    for (int j = 0; j < deg; ++j)
      m = fmaxf(m, lrelu(als[srcs[off0 + j] * 4 + head] + aldv));
    for (int j = 0; j < deg; ++j) {
      int s = srcs[off0 + j];
      float w = __expf(lrelu(als[s * 4 + head] + aldv) - m);
      den += w;
      num = fmaf(w, b2f(h1b[s * HID + t]), num);
    }
    out1b[n * HID + t] = f2b(fmaxf(num / den + b1[t], 0.f));
  }
}

// ---------- layer-2 softmax + aggregate + log_softmax: one wave per node ----------
__global__ __launch_bounds__(64) void k_agg2(const ushort_t* __restrict__ h2b,
                                             const float* __restrict__ als,
                                             const float* __restrict__ ald, const int* __restrict__ offs,
                                             const int* __restrict__ srcs, const float* __restrict__ b2,
                                             float* __restrict__ out) {
  __shared__ int sl[256];
  __shared__ float sw[256];
  int n = blockIdx.x, t = threadIdx.x;
  int off0 = offs[n], deg = offs[n + 1] - off0;
  float aldv = ald[n];
  float den = 0.f, num = 0.f;
  if (deg <= 256) {
    float lm = -INFINITY;
    for (int j = t; j < deg; j += 64) {
      int s = srcs[off0 + j];
      sl[j] = s;
      float e = lrelu(als[s] + aldv);
      sw[j] = e;
      lm = fmaxf(lm, e);
    }
    #pragma unroll
    for (int o = 32; o >= 1; o >>= 1) lm = fmaxf(lm, __shfl_xor(lm, o));
    __syncthreads();
    float ld = 0.f;
    for (int j = t; j < deg; j += 64) {
      float w = __expf(sw[j] - lm);
      sw[j] = w;
      ld += w;
    }
    #pragma unroll
    for (int o = 32; o >= 1; o >>= 1) ld += __shfl_xor(ld, o);
    den = ld;
    __syncthreads();
    int j = 0;
    for (; j + 4 <= deg; j += 4) {
      int s0 = sl[j], s1 = sl[j + 1], s2 = sl[j + 2], s3 = sl[j + 3];
      float v0 = b2f(h2b[s0 * ODIM + t]);
      float v1 = b2f(h2b[s1 * ODIM + t]);
      float v2 = b2f(h2b[s2 * ODIM + t]);
      float v3 = b2f(h2b[s3 * ODIM + t]);
      num = fmaf(sw[j],     v0, num);
      num = fmaf(sw[j + 1], v1, num);
      num = fmaf(sw[j + 2], v2, num);
      num = fmaf(sw[j + 3], v3, num);
    }
    for (; j < deg; ++j) num = fmaf(sw[j], b2f(h2b[sl[j] * ODIM + t]), num);
  } else {
    float lm = -INFINITY;
    for (int j = 0; j < deg; ++j) lm = fmaxf(lm, lrelu(als[srcs[off0 + j]] + aldv));
    for (int j = 0; j < deg; ++j) {
      int s = srcs[off0 + j];
      float w = __expf(lrelu(als[s] + aldv) - lm);
      den += w;
      num = fmaf(w, b2f(h2b[s * ODIM + t]), num);
    }
  }
  float val = num / den + b2[t];
  float mx = val;
  #pragma unroll
  for (int o = 32; o >= 1; o >>= 1) mx = fmaxf(mx, __shfl_xor(mx, o));
  float ex = __expf(val - mx);
  float sum = ex;
  #pragma unroll
  for (int o = 32; o >= 1; o >>= 1) sum += __shfl_xor(sum, o);
  out[n * ODIM + t] = (val - mx) - __logf(sum);
}

extern "C" void kernel_launch(void* const* d_in, const int* in_sizes, int n_in,
                              void* d_out, int out_size, void* d_ws, size_t ws_size,
                              hipStream_t stream) {
  const float* x   = (const float*)d_in[0];
  const void*  ei  = d_in[1];
  const float* W1  = (const float*)d_in[2];
  const float* as1 = (const float*)d_in[3];
  const float* ad1 = (const float*)d_in[4];
  const float* b1  = (const float*)d_in[5];
  const float* W2  = (const float*)d_in[6];
  const float* as2 = (const float*)d_in[7];
  const float* ad2 = (const float*)d_in[8];
  const float* b2  = (const float*)d_in[9];
  float* out = (float*)d_out;

  char* ws = (char*)d_ws;
  size_t o = 0;
  auto alloc = [&](size_t bytes) { void* p = (void*)(ws + o); o += (bytes + 255) & ~(size_t)255; return p; };
  ushort_t* h1b   = (ushort_t*)alloc((size_t)N_NODES * HID * 2);
  ushort_t* out1b = (ushort_t*)alloc((size_t)N_NODES * HID * 2);
  ushort_t* h2b   = (ushort_t*)alloc((size_t)N_NODES * ODIM * 2);
  ushort_t* Wt1   = (ushort_t*)alloc((size_t)128 * 128 * 2);
  ushort_t* Wt2   = (ushort_t*)alloc((size_t)64 * 128 * 2);
  float* als1 = (float*)alloc((size_t)N_NODES * 4 * 4);
  float* ald1 = (float*)alloc((size_t)N_NODES * 4 * 4);
  float* als2 = (float*)alloc((size_t)N_NODES * 4);
  float* ald2 = (float*)alloc((size_t)N_NODES * 4);
  int*   deg  = (int*)alloc((size_t)N_NODES * 4);
  int*   offs = (int*)alloc((size_t)(N_NODES + 1) * 4);
  int*   cur  = (int*)alloc((size_t)N_NODES * 4);
  int*   srcs = (int*)alloc((size_t)E_TOT * 4);
  int*   bsums= (int*)alloc((size_t)NB1 * 4);
  int*   flag = (int*)alloc(4);

  hipMemsetAsync(deg, 0, (size_t)N_NODES * 4, stream);
  hipMemsetAsync(cur, 0, (size_t)N_NODES * 4, stream);
  k_detect<<<1, 64, 0, stream>>>(ei, flag);

  int egrid = (E_TOT + 255) / 256;
  k_hist   <<<egrid, 256, 0, stream>>>(ei, flag, deg);
  k_scan1  <<<NB1,   256, 0, stream>>>(deg, offs, bsums);
  k_scan2  <<<1,     256, 0, stream>>>(bsums);
  k_scan3  <<<NB1,   256, 0, stream>>>(offs, bsums);
  k_scatter<<<egrid, 256, 0, stream>>>(ei, flag, offs, cur, srcs);
  k_prep   <<<64,    256, 0, stream>>>(W1, W2, Wt1, Wt2);

  k_mm1  <<<512, 256, 0, stream>>>(x, Wt1, h1b);
  k_al1  <<<N_NODES / 2, 256, 0, stream>>>(h1b, as1, ad1, als1, ald1);
  k_agg1 <<<N_NODES, 128, 0, stream>>>(h1b, als1, ald1, offs, srcs, b1, out1b);

  k_mm2  <<<512, 256, 0, stream>>>(out1b, Wt2, h2b);
  k_al2  <<<N_NODES / 4, 256, 0, stream>>>(h2b, as2, ad2, als2, ald2);
  k_agg2 <<<N_NODES, 64, 0, stream>>>(h2b, als2, ald2, offs, srcs, b2, out);
}

// Round 4
// 197.886 us; speedup vs baseline: 1.9471x; 1.2174x over previous
//
#include <hip/hip_runtime.h>
#include <hip/hip_bf16.h>
#include <math.h>

#define N_NODES 50000
#define N_EDGES 800000
#define E_TOT   (N_EDGES + N_NODES)
#define IN_DIM  128
#define HID     128      // HEADS*HIDDEN (layer-1 output width)
#define ODIM    64
#define NEG     0.2f
#define NB1     ((N_NODES + 255) / 256)   // scan blocks = 196
#define NCHUNK  ((N_NODES + 31) / 32)     // 32-node chunks for MFMA GEMMs

typedef short bf16x8 __attribute__((ext_vector_type(8)));
typedef float f32x4 __attribute__((ext_vector_type(4)));
typedef unsigned short ushort_t;

__device__ __forceinline__ float lrelu(float x) { return x >= 0.f ? x : NEG * x; }

// bf16 <-> f32 helpers (RNE rounding on store)
__device__ __forceinline__ unsigned short f2b(float v) {
  unsigned int b = __float_as_uint(v);
  b += 0x7fffu + ((b >> 16) & 1u);
  return (unsigned short)(b >> 16);
}
__device__ __forceinline__ float b2f(unsigned short u) {
  return __uint_as_float(((unsigned int)u) << 16);
}
__device__ __forceinline__ unsigned int f2b2(float lo, float hi) {
  union { __hip_bfloat162 h; unsigned int u; } cv;
  cv.h = __float22bfloat162_rn(make_float2(lo, hi));
  return cv.u;
}
// unpack packed 2xbf16 word
__device__ __forceinline__ float blo(unsigned int v) { return __uint_as_float(v << 16); }
__device__ __forceinline__ float bhi(unsigned int v) { return __uint_as_float(v & 0xffff0000u); }

// ---------- edge-index dtype detection (int32 vs int64) ----------
__global__ void k_detect(const void* ei, int* flag) {
  if (threadIdx.x == 0 && blockIdx.x == 0) {
    const int* p = (const int*)ei;
    int allz = 1;
    for (int i = 0; i < 64; ++i) if (p[2 * i + 1] != 0) { allz = 0; break; }
    *flag = allz;  // 1 => buffer is int64
  }
}

__device__ __forceinline__ int e_src(const void* ei, int f, int e) {
  if (e >= N_EDGES) return e - N_EDGES;              // self loop
  return f ? (int)((const long long*)ei)[e] : ((const int*)ei)[e];
}
__device__ __forceinline__ int e_dst(const void* ei, int f, int e) {
  if (e >= N_EDGES) return e - N_EDGES;              // self loop
  return f ? (int)((const long long*)ei)[N_EDGES + e] : ((const int*)ei)[N_EDGES + e];
}

// ---------- CSR build ----------
__global__ void k_hist(const void* ei, const int* flag, int* deg, int* rank) {
  int e = blockIdx.x * 256 + threadIdx.x;
  if (e >= E_TOT) return;
  int r = atomicAdd(&deg[e_dst(ei, *flag, e)], 1);
  rank[e] = r;
}

__global__ void k_scan1(const int* __restrict__ deg, int* __restrict__ offs, int* __restrict__ bsums) {
  __shared__ int sm[256];
  int t = threadIdx.x, i = blockIdx.x * 256 + t;
  int v = (i < N_NODES) ? deg[i] : 0;
  sm[t] = v;
  __syncthreads();
  for (int o = 1; o < 256; o <<= 1) {
    int add = (t >= o) ? sm[t - o] : 0;
    __syncthreads();
    sm[t] += add;
    __syncthreads();
  }
  if (i < N_NODES) offs[i] = sm[t] - v;   // exclusive
  if (t == 255) bsums[blockIdx.x] = sm[255];
}

__global__ void k_scan2(int* bsums) {
  __shared__ int sm[256];
  int t = threadIdx.x;
  int v = (t < NB1) ? bsums[t] : 0;
  sm[t] = v;
  __syncthreads();
  for (int o = 1; o < 256; o <<= 1) {
    int add = (t >= o) ? sm[t - o] : 0;
    __syncthreads();
    sm[t] += add;
    __syncthreads();
  }
  if (t < NB1) bsums[t] = sm[t] - v;      // exclusive
}

__global__ void k_scan3(int* __restrict__ offs, const int* __restrict__ bsums) {
  int i = blockIdx.x * 256 + threadIdx.x;
  if (i < N_NODES) offs[i] += bsums[blockIdx.x];
  if (i == 0) offs[N_NODES] = E_TOT;
}

__global__ void k_scatter(const void* ei, const int* __restrict__ flag, const int* __restrict__ offs,
                          const int* __restrict__ rank, int* __restrict__ srcs) {
  int e = blockIdx.x * 256 + threadIdx.x;
  if (e >= E_TOT) return;
  int f = *flag;
  int d = e_dst(ei, f, e);
  srcs[offs[d] + rank[e]] = e_src(ei, f, e);
}

// ---------- weight prep: bf16 W^T for both layers ----------
__global__ void k_prep(const float* __restrict__ W1, const float* __restrict__ W2,
                       ushort_t* __restrict__ Wt1, ushort_t* __restrict__ Wt2) {
  int i = blockIdx.x * 256 + threadIdx.x;
  if (i < 128 * 128) { int k = i >> 7, n = i & 127; Wt1[n * 128 + k] = f2b(W1[i]); }
  if (i < 128 * 64)  { int k = i >> 6, n = i & 63;  Wt2[n * 128 + k] = f2b(W2[i]); }
}

// ---------- MFMA GEMM1: h1b[N,128](bf16) = bf16(x[N,128]) @ W1 ----------
__global__ __launch_bounds__(256) void k_mm1(const float* __restrict__ x,
                                             const ushort_t* __restrict__ Wt,
                                             ushort_t* __restrict__ h1b) {
  __shared__ ushort_t xs[32 * 128];   // 8 KB
  int t = threadIdx.x;
  int w = t >> 6, l = t & 63;
  int lr = l & 15, lk = l >> 4;
  int nodeSub = (w & 1) * 16, colBase = (w >> 1) * 64;
  bf16x8 bfrag[4][4];
  #pragma unroll
  for (int ct = 0; ct < 4; ++ct)
    #pragma unroll
    for (int ks = 0; ks < 4; ++ks) {
      int n = colBase + ct * 16 + lr;
      int k = ks * 32 + lk * 8;
      bfrag[ct][ks] = *(const bf16x8*)&Wt[n * 128 + k];
    }
  int rr = t >> 3, c0 = (t & 7) * 16;   // staging: row, 16-elem col group
  for (int chunk = blockIdx.x; chunk < NCHUNK; chunk += gridDim.x) {
    int base = chunk * 32;
    int srcRow = base + rr; if (srcRow >= N_NODES) srcRow = N_NODES - 1;
    const float4* xr = (const float4*)&x[(size_t)srcRow * IN_DIM + c0];
    float4 f0 = xr[0], f1 = xr[1], f2 = xr[2], f3 = xr[3];
    uint4 w0, w1;
    w0.x = f2b2(f0.x, f0.y); w0.y = f2b2(f0.z, f0.w);
    w0.z = f2b2(f1.x, f1.y); w0.w = f2b2(f1.z, f1.w);
    w1.x = f2b2(f2.x, f2.y); w1.y = f2b2(f2.z, f2.w);
    w1.z = f2b2(f3.x, f3.y); w1.w = f2b2(f3.z, f3.w);
    char* xsb = (char*)xs;
    int swz = (rr & 7) << 4;
    *(uint4*)(xsb + rr * 256 + ((c0 * 2 +  0) ^ swz)) = w0;
    *(uint4*)(xsb + rr * 256 + ((c0 * 2 + 16) ^ swz)) = w1;
    __syncthreads();
    f32x4 acc[4] = {{0,0,0,0},{0,0,0,0},{0,0,0,0},{0,0,0,0}};
    int arow = nodeSub + lr;
    #pragma unroll
    for (int ks = 0; ks < 4; ++ks) {
      bf16x8 a = *(const bf16x8*)((const char*)xs + arow * 256 +
                                  ((ks * 64 + lk * 16) ^ ((arow & 7) << 4)));
      #pragma unroll
      for (int ct = 0; ct < 4; ++ct)
        acc[ct] = __builtin_amdgcn_mfma_f32_16x16x32_bf16(a, bfrag[ct][ks], acc[ct], 0, 0, 0);
    }
    __syncthreads();
    #pragma unroll
    for (int ct = 0; ct < 4; ++ct)
      #pragma unroll
      for (int r = 0; r < 4; ++r) {
        int node = base + nodeSub + lk * 4 + r;
        if (node < N_NODES)
          h1b[(size_t)node * HID + colBase + ct * 16 + lr] = f2b(acc[ct][r]);
      }
  }
}

// ---------- MFMA GEMM2: h2b[N,64](bf16) = out1b[N,128] @ W2 ----------
__global__ __launch_bounds__(256) void k_mm2(const ushort_t* __restrict__ xb,
                                             const ushort_t* __restrict__ Wt,
                                             ushort_t* __restrict__ h2b) {
  __shared__ ushort_t xs[32 * 128];   // 8 KB
  int t = threadIdx.x;
  int w = t >> 6, l = t & 63;
  int lr = l & 15, lk = l >> 4;
  int nodeSub = (w & 1) * 16, colBase = (w >> 1) * 32;
  bf16x8 bfrag[2][4];
  #pragma unroll
  for (int ct = 0; ct < 2; ++ct)
    #pragma unroll
    for (int ks = 0; ks < 4; ++ks) {
      int n = colBase + ct * 16 + lr;
      int k = ks * 32 + lk * 8;
      bfrag[ct][ks] = *(const bf16x8*)&Wt[n * 128 + k];
    }
  int rr = t >> 3, c0 = (t & 7) * 16;
  for (int chunk = blockIdx.x; chunk < NCHUNK; chunk += gridDim.x) {
    int base = chunk * 32;
    int srcRow = base + rr; if (srcRow >= N_NODES) srcRow = N_NODES - 1;
    const uint4* xr = (const uint4*)&xb[(size_t)srcRow * HID + c0];
    uint4 w0 = xr[0], w1 = xr[1];
    char* xsb = (char*)xs;
    int swz = (rr & 7) << 4;
    *(uint4*)(xsb + rr * 256 + ((c0 * 2 +  0) ^ swz)) = w0;
    *(uint4*)(xsb + rr * 256 + ((c0 * 2 + 16) ^ swz)) = w1;
    __syncthreads();
    f32x4 acc[2] = {{0,0,0,0},{0,0,0,0}};
    int arow = nodeSub + lr;
    #pragma unroll
    for (int ks = 0; ks < 4; ++ks) {
      bf16x8 a = *(const bf16x8*)((const char*)xs + arow * 256 +
                                  ((ks * 64 + lk * 16) ^ ((arow & 7) << 4)));
      #pragma unroll
      for (int ct = 0; ct < 2; ++ct)
        acc[ct] = __builtin_amdgcn_mfma_f32_16x16x32_bf16(a, bfrag[ct][ks], acc[ct], 0, 0, 0);
    }
    __syncthreads();
    #pragma unroll
    for (int ct = 0; ct < 2; ++ct)
      #pragma unroll
      for (int r = 0; r < 4; ++r) {
        int node = base + nodeSub + lk * 4 + r;
        if (node < N_NODES)
          h2b[(size_t)node * ODIM + colBase + ct * 16 + lr] = f2b(acc[ct][r]);
      }
  }
}

// ---------- attention logits: 16B loads, 8 cols/lane ----------
__global__ __launch_bounds__(256) void k_al1(const ushort_t* __restrict__ h1b,
                                             const float* __restrict__ asrc,
                                             const float* __restrict__ adst, float* __restrict__ als,
                                             float* __restrict__ ald) {
  int t = threadIdx.x;
  int n = blockIdx.x * 16 + (t >> 4);
  int c8 = (t & 15) * 8;
  uint4 v = *(const uint4*)&h1b[(size_t)n * HID + c8];
  float4 a0 = *(const float4*)&asrc[c8], a1 = *(const float4*)&asrc[c8 + 4];
  float4 d0 = *(const float4*)&adst[c8], d1 = *(const float4*)&adst[c8 + 4];
  float f0 = blo(v.x), f1 = bhi(v.x), f2 = blo(v.y), f3 = bhi(v.y);
  float f4 = blo(v.z), f5 = bhi(v.z), f6 = blo(v.w), f7 = bhi(v.w);
  float s = f0*a0.x + f1*a0.y + f2*a0.z + f3*a0.w + f4*a1.x + f5*a1.y + f6*a1.z + f7*a1.w;
  float d = f0*d0.x + f1*d0.y + f2*d0.z + f3*d0.w + f4*d1.x + f5*d1.y + f6*d1.z + f7*d1.w;
  s += __shfl_xor(s, 1); s += __shfl_xor(s, 2);
  d += __shfl_xor(d, 1); d += __shfl_xor(d, 2);
  if ((t & 3) == 0) {
    int head = (t & 15) >> 2;
    als[n * 4 + head] = s;
    ald[n * 4 + head] = d;
  }
}

__global__ __launch_bounds__(256) void k_al2(const ushort_t* __restrict__ h2b,
                                             const float* __restrict__ asrc,
                                             const float* __restrict__ adst, float* __restrict__ als,
                                             float* __restrict__ ald) {
  int t = threadIdx.x;
  int n = blockIdx.x * 32 + (t >> 3);
  if (n >= N_NODES) return;
  int c8 = (t & 7) * 8;
  uint4 v = *(const uint4*)&h2b[(size_t)n * ODIM + c8];
  float4 a0 = *(const float4*)&asrc[c8], a1 = *(const float4*)&asrc[c8 + 4];
  float4 d0 = *(const float4*)&adst[c8], d1 = *(const float4*)&adst[c8 + 4];
  float f0 = blo(v.x), f1 = bhi(v.x), f2 = blo(v.y), f3 = bhi(v.y);
  float f4 = blo(v.z), f5 = bhi(v.z), f6 = blo(v.w), f7 = bhi(v.w);
  float s = f0*a0.x + f1*a0.y + f2*a0.z + f3*a0.w + f4*a1.x + f5*a1.y + f6*a1.z + f7*a1.w;
  float d = f0*d0.x + f1*d0.y + f2*d0.z + f3*d0.w + f4*d1.x + f5*d1.y + f6*d1.z + f7*d1.w;
  s += __shfl_xor(s, 1); s += __shfl_xor(s, 2); s += __shfl_xor(s, 4);
  d += __shfl_xor(d, 1); d += __shfl_xor(d, 2); d += __shfl_xor(d, 4);
  if ((t & 7) == 0) { als[n] = s; ald[n] = d; }
}

// ---------- layer-1 softmax + aggregate: one block (128 thr) per dst node ----------
// gather: 4 cols/lane via uint2 (32 lanes = full 256B row), 4 edge groups in parallel
__global__ __launch_bounds__(128) void k_agg1(const ushort_t* __restrict__ h1b,
                                              const float* __restrict__ als,
                                              const float* __restrict__ ald, const int* __restrict__ offs,
                                              const int* __restrict__ srcs, const float* __restrict__ b1,
                                              ushort_t* __restrict__ out1b) {
  __shared__ int sl[256];            // pre-shifted byte offsets (s*256)
  __shared__ float sw[4 * 256];
  __shared__ float redm[2][4];
  __shared__ float redd[2][4];
  __shared__ float rednum[32][4];
  int n = blockIdx.x, t = threadIdx.x;
  int w = t >> 6, l = t & 63, lane32 = l & 31;
  int off0 = offs[n], deg = offs[n + 1] - off0;

  if (deg <= 256) {
    const float4* als4 = (const float4*)als;
    float4 ad = ((const float4*)ald)[n];
    // pass A: edge-parallel logits + local max (all 4 heads per thread)
    float lm0 = -INFINITY, lm1 = -INFINITY, lm2 = -INFINITY, lm3 = -INFINITY;
    for (int j = t; j < deg; j += 128) {
      int s = srcs[off0 + j];
      sl[j] = s << 8;                // byte offset into h1b
      float4 a = als4[s];
      float e0 = lrelu(a.x + ad.x), e1 = lrelu(a.y + ad.y);
      float e2 = lrelu(a.z + ad.z), e3 = lrelu(a.w + ad.w);
      sw[0 * 256 + j] = e0; sw[1 * 256 + j] = e1;
      sw[2 * 256 + j] = e2; sw[3 * 256 + j] = e3;
      lm0 = fmaxf(lm0, e0); lm1 = fmaxf(lm1, e1);
      lm2 = fmaxf(lm2, e2); lm3 = fmaxf(lm3, e3);
    }
    #pragma unroll
    for (int o = 32; o >= 1; o >>= 1) {
      lm0 = fmaxf(lm0, __shfl_xor(lm0, o)); lm1 = fmaxf(lm1, __shfl_xor(lm1, o));
      lm2 = fmaxf(lm2, __shfl_xor(lm2, o)); lm3 = fmaxf(lm3, __shfl_xor(lm3, o));
    }
    if (l == 0) { redm[w][0] = lm0; redm[w][1] = lm1; redm[w][2] = lm2; redm[w][3] = lm3; }
    __syncthreads();
    float m0 = fmaxf(redm[0][0], redm[1][0]), m1 = fmaxf(redm[0][1], redm[1][1]);
    float m2 = fmaxf(redm[0][2], redm[1][2]), m3 = fmaxf(redm[0][3], redm[1][3]);
    // pass B: edge-parallel exp + local denom
    float d0 = 0.f, d1 = 0.f, d2 = 0.f, d3 = 0.f;
    for (int j = t; j < deg; j += 128) {
      float w0 = __expf(sw[0 * 256 + j] - m0); sw[0 * 256 + j] = w0; d0 += w0;
      float w1 = __expf(sw[1 * 256 + j] - m1); sw[1 * 256 + j] = w1; d1 += w1;
      float w2 = __expf(sw[2 * 256 + j] - m2); sw[2 * 256 + j] = w2; d2 += w2;
      float w3 = __expf(sw[3 * 256 + j] - m3); sw[3 * 256 + j] = w3; d3 += w3;
    }
    #pragma unroll
    for (int o = 32; o >= 1; o >>= 1) {
      d0 += __shfl_xor(d0, o); d1 += __shfl_xor(d1, o);
      d2 += __shfl_xor(d2, o); d3 += __shfl_xor(d3, o);
    }
    if (l == 0) { redd[w][0] = d0; redd[w][1] = d1; redd[w][2] = d2; redd[w][3] = d3; }
    __syncthreads();
    // pass C: wide gather. group g handles edges j = g, g+4, ...
    int g = w * 2 + (l >> 5);
    int headIdx = lane32 >> 3;               // (lane32*4)>>5
    const float* swh = &sw[headIdx * 256];
    const char* hb = (const char*)h1b + lane32 * 8;   // col byte offset
    float num0 = 0.f, num1 = 0.f, num2 = 0.f, num3 = 0.f;
    int j = g;
    for (; j + 4 < deg; j += 8) {
      int b0 = sl[j], b1o = sl[j + 4];
      float w0 = swh[j], w1 = swh[j + 4];
      uint2 v0 = *(const uint2*)(hb + b0);
      uint2 v1 = *(const uint2*)(hb + b1o);
      num0 = fmaf(w0, blo(v0.x), num0); num1 = fmaf(w0, bhi(v0.x), num1);
      num2 = fmaf(w0, blo(v0.y), num2); num3 = fmaf(w0, bhi(v0.y), num3);
      num0 = fmaf(w1, blo(v1.x), num0); num1 = fmaf(w1, bhi(v1.x), num1);
      num2 = fmaf(w1, blo(v1.y), num2); num3 = fmaf(w1, bhi(v1.y), num3);
    }
    if (j < deg) {
      int b0 = sl[j];
      float w0 = swh[j];
      uint2 v0 = *(const uint2*)(hb + b0);
      num0 = fmaf(w0, blo(v0.x), num0); num1 = fmaf(w0, bhi(v0.x), num1);
      num2 = fmaf(w0, blo(v0.y), num2); num3 = fmaf(w0, bhi(v0.y), num3);
    }
    // combine half-waves within wave
    num0 += __shfl_xor(num0, 32); num1 += __shfl_xor(num1, 32);
    num2 += __shfl_xor(num2, 32); num3 += __shfl_xor(num3, 32);
    if (w == 1 && l < 32) {
      rednum[l][0] = num0; rednum[l][1] = num1; rednum[l][2] = num2; rednum[l][3] = num3;
    }
    __syncthreads();
    if (w == 0 && l < 32) {
      num0 += rednum[l][0]; num1 += rednum[l][1]; num2 += rednum[l][2]; num3 += rednum[l][3];
      float den = redd[0][headIdx] + redd[1][headIdx];
      int c4 = lane32 * 4;
      float4 bb = *(const float4*)&b1[c4];
      float o0 = fmaxf(num0 / den + bb.x, 0.f);
      float o1 = fmaxf(num1 / den + bb.y, 0.f);
      float o2 = fmaxf(num2 / den + bb.z, 0.f);
      float o3 = fmaxf(num3 / den + bb.w, 0.f);
      uint2 pk; pk.x = f2b2(o0, o1); pk.y = f2b2(o2, o3);
      *(uint2*)&out1b[(size_t)n * HID + c4] = pk;
    }
  } else {  // fallback (not hit at this graph size)
    int head = t >> 5;
    float aldv = ald[n * 4 + head];
    float m = -INFINITY, den = 0.f, num = 0.f;
    for (int j = 0; j < deg; ++j)
      m = fmaxf(m, lrelu(als[srcs[off0 + j] * 4 + head] + aldv));
    for (int j = 0; j < deg; ++j) {
      int s = srcs[off0 + j];
      float wq = __expf(lrelu(als[s * 4 + head] + aldv) - m);
      den += wq;
      num = fmaf(wq, b2f(h1b[(size_t)s * HID + t]), num);
    }
    out1b[(size_t)n * HID + t] = f2b(fmaxf(num / den + b1[t], 0.f));
  }
}

// ---------- layer-2 softmax + aggregate + log_softmax: one wave per node ----------
__global__ __launch_bounds__(64) void k_agg2(const ushort_t* __restrict__ h2b,
                                             const float* __restrict__ als,
                                             const float* __restrict__ ald, const int* __restrict__ offs,
                                             const int* __restrict__ srcs, const float* __restrict__ b2,
                                             float* __restrict__ out) {
  __shared__ int sl[256];
  __shared__ float sw[256];
  int n = blockIdx.x, t = threadIdx.x;
  int off0 = offs[n], deg = offs[n + 1] - off0;
  float aldv = ald[n];
  if (deg <= 256) {
    float lm = -INFINITY;
    for (int j = t; j < deg; j += 64) {
      int s = srcs[off0 + j];
      sl[j] = s << 7;                 // byte offset into h2b
      float e = lrelu(als[s] + aldv);
      sw[j] = e;
      lm = fmaxf(lm, e);
    }
    #pragma unroll
    for (int o = 32; o >= 1; o >>= 1) lm = fmaxf(lm, __shfl_xor(lm, o));
    __syncthreads();
    float ld = 0.f;
    for (int j = t; j < deg; j += 64) {
      float wq = __expf(sw[j] - lm);
      sw[j] = wq;
      ld += wq;
    }
    #pragma unroll
    for (int o = 32; o >= 1; o >>= 1) ld += __shfl_xor(ld, o);
    float den = ld;
    __syncthreads();
    // wide gather: 2 cols/lane via uint, 2 edge groups
    int g = t >> 5, lane32 = t & 31;
    const char* hb = (const char*)h2b + lane32 * 4;
    float num0 = 0.f, num1 = 0.f;
    int j = g;
    for (; j + 2 < deg; j += 4) {
      int b0 = sl[j], b1o = sl[j + 2];
      float w0 = sw[j], w1 = sw[j + 2];
      unsigned int v0 = *(const unsigned int*)(hb + b0);
      unsigned int v1 = *(const unsigned int*)(hb + b1o);
      num0 = fmaf(w0, blo(v0), num0); num1 = fmaf(w0, bhi(v0), num1);
      num0 = fmaf(w1, blo(v1), num0); num1 = fmaf(w1, bhi(v1), num1);
    }
    if (j < deg) {
      unsigned int v0 = *(const unsigned int*)(hb + sl[j]);
      float w0 = sw[j];
      num0 = fmaf(w0, blo(v0), num0); num1 = fmaf(w0, bhi(v0), num1);
    }
    num0 += __shfl_xor(num0, 32);
    num1 += __shfl_xor(num1, 32);
    if (t < 32) {
      int c2 = lane32 * 2;
      float2 bb = *(const float2*)&b2[c2];
      float val0 = num0 / den + bb.x;
      float val1 = num1 / den + bb.y;
      float mx = fmaxf(val0, val1);
      #pragma unroll
      for (int o = 16; o >= 1; o >>= 1) mx = fmaxf(mx, __shfl_xor(mx, o));
      float sum = __expf(val0 - mx) + __expf(val1 - mx);
      #pragma unroll
      for (int o = 16; o >= 1; o >>= 1) sum += __shfl_xor(sum, o);
      float ls = __logf(sum);
      float2 res; res.x = (val0 - mx) - ls; res.y = (val1 - mx) - ls;
      *(float2*)&out[(size_t)n * ODIM + c2] = res;
    }
  } else {  // fallback
    float lm = -INFINITY;
    float den = 0.f, num = 0.f;
    for (int j = 0; j < deg; ++j) lm = fmaxf(lm, lrelu(als[srcs[off0 + j]] + aldv));
    for (int j = 0; j < deg; ++j) {
      int s = srcs[off0 + j];
      float wq = __expf(lrelu(als[s] + aldv) - lm);
      den += wq;
      num = fmaf(wq, b2f(h2b[(size_t)s * ODIM + t]), num);
    }
    float val = num / den + b2[t];
    float mx = val;
    #pragma unroll
    for (int o = 32; o >= 1; o >>= 1) mx = fmaxf(mx, __shfl_xor(mx, o));
    float ex = __expf(val - mx);
    float sum = ex;
    #pragma unroll
    for (int o = 32; o >= 1; o >>= 1) sum += __shfl_xor(sum, o);
    out[(size_t)n * ODIM + t] = (val - mx) - __logf(sum);
  }
}

extern "C" void kernel_launch(void* const* d_in, const int* in_sizes, int n_in,
                              void* d_out, int out_size, void* d_ws, size_t ws_size,
                              hipStream_t stream) {
  const float* x   = (const float*)d_in[0];
  const void*  ei  = d_in[1];
  const float* W1  = (const float*)d_in[2];
  const float* as1 = (const float*)d_in[3];
  const float* ad1 = (const float*)d_in[4];
  const float* b1  = (const float*)d_in[5];
  const float* W2  = (const float*)d_in[6];
  const float* as2 = (const float*)d_in[7];
  const float* ad2 = (const float*)d_in[8];
  const float* b2  = (const float*)d_in[9];
  float* out = (float*)d_out;

  char* ws = (char*)d_ws;
  size_t o = 0;
  auto alloc = [&](size_t bytes) { void* p = (void*)(ws + o); o += (bytes + 255) & ~(size_t)255; return p; };
  ushort_t* h1b   = (ushort_t*)alloc((size_t)N_NODES * HID * 2);
  ushort_t* out1b = (ushort_t*)alloc((size_t)N_NODES * HID * 2);
  ushort_t* h2b   = (ushort_t*)alloc((size_t)N_NODES * ODIM * 2);
  ushort_t* Wt1   = (ushort_t*)alloc((size_t)128 * 128 * 2);
  ushort_t* Wt2   = (ushort_t*)alloc((size_t)64 * 128 * 2);
  float* als1 = (float*)alloc((size_t)N_NODES * 4 * 4);
  float* ald1 = (float*)alloc((size_t)N_NODES * 4 * 4);
  float* als2 = (float*)alloc((size_t)N_NODES * 4);
  float* ald2 = (float*)alloc((size_t)N_NODES * 4);
  int*   deg  = (int*)alloc((size_t)N_NODES * 4);
  int*   offs = (int*)alloc((size_t)(N_NODES + 1) * 4);
  int*   rank = (int*)alloc((size_t)E_TOT * 4);
  int*   srcs = (int*)alloc((size_t)E_TOT * 4);
  int*   bsums= (int*)alloc((size_t)NB1 * 4);
  int*   flag = (int*)alloc(4);

  hipMemsetAsync(deg, 0, (size_t)N_NODES * 4, stream);
  k_detect<<<1, 64, 0, stream>>>(ei, flag);

  int egrid = (E_TOT + 255) / 256;
  k_hist   <<<egrid, 256, 0, stream>>>(ei, flag, deg, rank);
  k_scan1  <<<NB1,   256, 0, stream>>>(deg, offs, bsums);
  k_scan2  <<<1,     256, 0, stream>>>(bsums);
  k_scan3  <<<NB1,   256, 0, stream>>>(offs, bsums);
  k_scatter<<<egrid, 256, 0, stream>>>(ei, flag, offs, rank, srcs);
  k_prep   <<<64,    256, 0, stream>>>(W1, W2, Wt1, Wt2);

  k_mm1  <<<512, 256, 0, stream>>>(x, Wt1, h1b);
  k_al1  <<<N_NODES / 16, 256, 0, stream>>>(h1b, as1, ad1, als1, ald1);
  k_agg1 <<<N_NODES, 128, 0, stream>>>(h1b, als1, ald1, offs, srcs, b1, out1b);

  k_mm2  <<<512, 256, 0, stream>>>(out1b, Wt2, h2b);
  k_al2  <<<(N_NODES + 31) / 32, 256, 0, stream>>>(h2b, as2, ad2, als2, ald2);
  k_agg2 <<<N_NODES, 64, 0, stream>>>(h2b, als2, ald2, offs, srcs, b2, out);
}